// Round 2
// baseline (63.423 us; speedup 1.0000x reference)
//
#include <hip/hip_runtime.h>
#include <hip/hip_bf16.h>

// Problem: B=8192, A=128, F=16, S=8
// x[b,a,:] = c[b,a,:] - q[b,a,:] * lam[b, seg[b,a]]
// lam[b,s] = (sum_{a: seg=s} c.q - charges[b,s]) / (sum_{a: seg=s} q.q)
//
// Structure: one WAVE per batch, no __syncthreads. 256-thread blocks = 4
// waves = 4 batches; grid = B/4 = 2048. Per-wave LDS slots for segment sums
// (DS ops from one wave are program-ordered -> waitcnt instead of barrier).

#define B_ 8192
#define A_ 128
#define F_ 16
#define S_ 8

#define WAVES_PER_BLOCK 4
#define VEC_PER_BATCH (A_ * F_ / 4)   // 512 float4 per batch
#define VEC_PER_LANE  (VEC_PER_BATCH / 64)  // 8

__global__ __launch_bounds__(64 * WAVES_PER_BLOCK) void qp_seg_norm_kernel(
    const float* __restrict__ c_iso,
    const float* __restrict__ int_iso,
    const int*   __restrict__ segment,
    const float* __restrict__ charges,
    float*       __restrict__ out)
{
    const int w    = threadIdx.x >> 6;       // wave in block
    const int lane = threadIdx.x & 63;
    const int b    = blockIdx.x * WAVES_PER_BLOCK + w;   // batch index

    // per-wave segment accumulators
    __shared__ float s_qc[WAVES_PER_BLOCK][S_];
    __shared__ float s_qq[WAVES_PER_BLOCK][S_];
    __shared__ float s_lam[WAVES_PER_BLOCK][S_];

    if (lane < S_) { s_qc[w][lane] = 0.0f; s_qq[w][lane] = 0.0f; }
    // same-wave DS ordering: no barrier needed; ops below are program-ordered

    const size_t vbase = (size_t)b * VEC_PER_BATCH;      // float4 index
    const float4* cp = reinterpret_cast<const float4*>(c_iso)   + vbase;
    const float4* qp = reinterpret_cast<const float4*>(int_iso) + vbase;
    const int*    sp = segment + (size_t)b * A_;

    float4 cv[VEC_PER_LANE], qv[VEC_PER_LANE];
    int    sg[VEC_PER_LANE];

    // Issue ALL loads up front (coalesced: lane l -> float4 j*64+l).
#pragma unroll
    for (int j = 0; j < VEC_PER_LANE; ++j) {
        const int idx = j * 64 + lane;        // float4 index within batch
        cv[j] = cp[idx];
        qv[j] = qp[idx];
        sg[j] = sp[idx >> 2];                 // atom = idx/4 (4 float4 per atom)
    }

    // Per-group dot products -> wave-private LDS atomic accumulation.
#pragma unroll
    for (int j = 0; j < VEC_PER_LANE; ++j) {
        const float cq = cv[j].x * qv[j].x + cv[j].y * qv[j].y
                       + cv[j].z * qv[j].z + cv[j].w * qv[j].w;
        const float qq = qv[j].x * qv[j].x + qv[j].y * qv[j].y
                       + qv[j].z * qv[j].z + qv[j].w * qv[j].w;
        atomicAdd(&s_qc[w][sg[j]], cq);
        atomicAdd(&s_qq[w][sg[j]], qq);
    }

    // Wait for this wave's DS atomics (no cross-wave sharing -> no barrier).
    __threadfence_block();

    if (lane < S_) {
        const float charge = charges[(size_t)b * S_ + lane];
        s_lam[w][lane] = (s_qc[w][lane] - charge) / s_qq[w][lane];
    }
    __threadfence_block();

    float4* op = reinterpret_cast<float4*>(out) + vbase;
#pragma unroll
    for (int j = 0; j < VEC_PER_LANE; ++j) {
        const float lam = s_lam[w][sg[j]];    // broadcast-friendly LDS read
        const int idx = j * 64 + lane;
        float4 r;
        r.x = cv[j].x - qv[j].x * lam;
        r.y = cv[j].y - qv[j].y * lam;
        r.z = cv[j].z - qv[j].z * lam;
        r.w = cv[j].w - qv[j].w * lam;
        op[idx] = r;
    }
}

extern "C" void kernel_launch(void* const* d_in, const int* in_sizes, int n_in,
                              void* d_out, int out_size, void* d_ws, size_t ws_size,
                              hipStream_t stream) {
    const float* c_iso   = (const float*)d_in[0];
    const float* int_iso = (const float*)d_in[1];
    const int*   segment = (const int*)d_in[2];
    const float* charges = (const float*)d_in[3];
    float* out = (float*)d_out;

    qp_seg_norm_kernel<<<B_ / WAVES_PER_BLOCK, 64 * WAVES_PER_BLOCK, 0, stream>>>(
        c_iso, int_iso, segment, charges, out);
}

// Round 3
// 36.085 us; speedup vs baseline: 1.7576x; 1.7576x over previous
//
#include <hip/hip_runtime.h>
#include <hip/hip_bf16.h>

// Problem: B=8192, A=128, F=16, S=8
// x[b,a,:] = c[b,a,:] - q[b,a,:] * lam[b, seg[b,a]]
// lam[b,s] = (sum_{a: seg=s} c.q - charges[b,s]) / (sum_{a: seg=s} q.q)
//
// R3: one wave per batch. NO LDS, NO barriers, NO atomics.
// Per-segment sums in registers (branchless masked accumulate, compile-time
// indices only), cross-lane butterfly reduce, lambda via shfl broadcast.

#define B_ 8192
#define A_ 128
#define F_ 16
#define S_ 8

#define WPB 4                       // waves (=batches) per block
#define VPB (A_ * F_ / 4)           // 512 float4 per batch
#define VPL (VPB / 64)              // 8 float4 per lane

__global__ __launch_bounds__(64 * WPB) void qp_seg_norm_kernel(
    const float* __restrict__ c_iso,
    const float* __restrict__ int_iso,
    const int*   __restrict__ segment,
    const float* __restrict__ charges,
    float*       __restrict__ out)
{
    const int w    = threadIdx.x >> 6;
    const int lane = threadIdx.x & 63;
    const int b    = blockIdx.x * WPB + w;

    // Hoist the charge load: only needed after the butterfly, issue it now.
    float charge = 0.0f;
    if (lane < S_) charge = charges[(size_t)b * S_ + lane];

    const float4* cp = reinterpret_cast<const float4*>(c_iso)   + (size_t)b * VPB;
    const float4* qp = reinterpret_cast<const float4*>(int_iso) + (size_t)b * VPB;
    const int*    sp = segment + (size_t)b * A_;

    float4 cv[VPL], qv[VPL];
    unsigned sgp = 0;                // 8 segment ids packed 4 bits each

#pragma unroll
    for (int j = 0; j < VPL; ++j) {
        const int v = j * 64 + lane;           // float4 index: contiguous/instr
        cv[j] = cp[v];
        qv[j] = qp[v];
        sgp |= ((unsigned)sp[v >> 2]) << (4 * j);   // atom = v/4
    }

    // Branchless per-segment accumulation into registers.
    float aqc[S_], aqq[S_];
#pragma unroll
    for (int s = 0; s < S_; ++s) { aqc[s] = 0.0f; aqq[s] = 0.0f; }

#pragma unroll
    for (int j = 0; j < VPL; ++j) {
        const float cq = cv[j].x * qv[j].x + cv[j].y * qv[j].y
                       + cv[j].z * qv[j].z + cv[j].w * qv[j].w;
        const float qq = qv[j].x * qv[j].x + qv[j].y * qv[j].y
                       + qv[j].z * qv[j].z + qv[j].w * qv[j].w;
        const int sj = (int)((sgp >> (4 * j)) & 7u);
#pragma unroll
        for (int s = 0; s < S_; ++s) {
            const bool m = (sj == s);
            aqc[s] += m ? cq : 0.0f;
            aqq[s] += m ? qq : 0.0f;
        }
    }

    // Butterfly all-reduce across the wave (16 values x 6 steps).
#pragma unroll
    for (int m = 1; m < 64; m <<= 1) {
#pragma unroll
        for (int s = 0; s < S_; ++s) {
            aqc[s] += __shfl_xor(aqc[s], m, 64);
            aqq[s] += __shfl_xor(aqq[s], m, 64);
        }
    }

    // lane s (s<8) computes lam[s]; select acc[lane] branchlessly.
    float qcsel = aqc[0], qqsel = aqq[0];
#pragma unroll
    for (int s = 1; s < S_; ++s) {
        const bool m = (lane == s);
        qcsel = m ? aqc[s] : qcsel;
        qqsel = m ? aqq[s] : qqsel;
    }
    const float lamv = (qcsel - charge) / qqsel;   // garbage in lanes >= 8, never read

    float4* op = reinterpret_cast<float4*>(out) + (size_t)b * VPB;
#pragma unroll
    for (int j = 0; j < VPL; ++j) {
        const int sj = (int)((sgp >> (4 * j)) & 7u);
        const float lam = __shfl(lamv, sj, 64);    // ds_bpermute broadcast
        const int v = j * 64 + lane;
        float4 r;
        r.x = cv[j].x - qv[j].x * lam;
        r.y = cv[j].y - qv[j].y * lam;
        r.z = cv[j].z - qv[j].z * lam;
        r.w = cv[j].w - qv[j].w * lam;
        op[v] = r;
    }
}

extern "C" void kernel_launch(void* const* d_in, const int* in_sizes, int n_in,
                              void* d_out, int out_size, void* d_ws, size_t ws_size,
                              hipStream_t stream) {
    const float* c_iso   = (const float*)d_in[0];
    const float* int_iso = (const float*)d_in[1];
    const int*   segment = (const int*)d_in[2];
    const float* charges = (const float*)d_in[3];
    float* out = (float*)d_out;

    qp_seg_norm_kernel<<<B_ / WPB, 64 * WPB, 0, stream>>>(
        c_iso, int_iso, segment, charges, out);
}